// Round 1
// baseline (47289.072 us; speedup 1.0000x reference)
//
#include <hip/hip_runtime.h>

#define T_STEPS 2048
#define BATCH   256
#define ISZ     512
#define HSZ     512
#define GSZ     2048   // 4*H
#define KSZ     1024   // I + H

using bf16x8 = __attribute__((ext_vector_type(8))) __bf16;
using f32x4  = __attribute__((ext_vector_type(4))) float;

// ---------------- workspace layout (bytes) ----------------
// 0        : W_cat  bf16 [2048][1024]   (4 MB)
// 4194304  : bias   f32  [2048]         (8 KB)
// 4202496  : h0     bf16 [256][512]     (256 KB)
// 4464640  : h1     bf16 [256][512]     (256 KB)
// 4726784  : c      f32  [256][512]     (512 KB)
// total 5251072 bytes

__device__ __forceinline__ unsigned short f2bf(float f) {
    unsigned int u = __float_as_uint(f);
    unsigned int r = (u + 0x7FFFu + ((u >> 16) & 1u)) >> 16;
    return (unsigned short)r;
}

__device__ __forceinline__ float sigf(float x) {
    return 1.0f / (1.0f + __expf(-x));
}
__device__ __forceinline__ float tanh_f(float x) {
    // 2*sigmoid(2x)-1 ; no overflow/NaN for large |x|
    return 2.0f / (1.0f + __expf(-2.0f * x)) - 1.0f;
}

// ---------------- pack W_ih|W_hh -> bf16 W_cat ----------------
__global__ void pack_weights(const float* __restrict__ Wih,
                             const float* __restrict__ Whh,
                             unsigned short* __restrict__ Wcat) {
    int gid = blockIdx.x * blockDim.x + threadIdx.x;   // 0 .. 524287
    int n   = gid >> 8;                                // 0..2047
    int k4  = (gid & 255) * 4;                         // 0..1020
    const float* src = (k4 < ISZ) ? (Wih + (size_t)n * ISZ + k4)
                                  : (Whh + (size_t)n * HSZ + (k4 - ISZ));
    float4 v = *(const float4*)src;
    ushort4 o;
    o.x = f2bf(v.x); o.y = f2bf(v.y); o.z = f2bf(v.z); o.w = f2bf(v.w);
    *(ushort4*)(Wcat + (size_t)n * KSZ + k4) = o;
}

// ---------------- init: out=b_out, c=0, h0=0, bias=b_ih+b_hh ----------------
__global__ void init_state(float* __restrict__ out, const float* __restrict__ b_out,
                           float* __restrict__ c, unsigned short* __restrict__ h0,
                           float* __restrict__ bias,
                           const float* __restrict__ b_ih, const float* __restrict__ b_hh) {
    int gid = blockIdx.x * blockDim.x + threadIdx.x;
    float bo = b_out[0];
    if (gid < T_STEPS * BATCH) out[gid] = bo;
    if (gid < BATCH * HSZ) { c[gid] = 0.0f; h0[gid] = 0; }
    if (gid < GSZ) bias[gid] = b_ih[gid] + b_hh[gid];
}

// ---------------- one LSTM timestep ----------------
// grid: (32 j-blocks, 8 b-tiles), block: 256 threads (4 waves)
// wave w computes gate w for hidden cols [jb*16, jb*16+16), rows [b0, b0+32)
#define ROWB 2064   // LDS row stride in bytes (1024 bf16 + 16B pad -> conflict-free b128 reads)

__launch_bounds__(256)
__global__ void lstm_step(const float* __restrict__ x,            // [T][B][I]
                          const unsigned short* __restrict__ Wcat,// [2048][1024] bf16
                          const float* __restrict__ bias,         // [2048]
                          const float* __restrict__ Wout,         // [512]
                          const unsigned short* __restrict__ h_prev, // [256][512] bf16
                          unsigned short* __restrict__ h_next,
                          float* __restrict__ c,                  // [256][512]
                          float* __restrict__ out,                // [T][B]
                          int t) {
    __shared__ __align__(16) char Alds[32 * ROWB];   // 66048 B
    __shared__ float gbuf[4][32][16];                // 8192 B

    const int tid  = threadIdx.x;
    const int lane = tid & 63;
    const int w    = tid >> 6;
    const int jb   = blockIdx.x;        // 0..31
    const int b0   = blockIdx.y * 32;   // 0..224

    // ---- stage A = [x_t | h_prev] rows b0..b0+31 into LDS as bf16 ----
    {
        const int k4 = tid * 4;                       // 0..1020
        const bool isX = (k4 < ISZ);
        const char* gsrc;
        int srcStride;
        if (isX) {
            gsrc = (const char*)(x + ((size_t)t * BATCH + b0) * ISZ + k4);
            srcStride = ISZ * 4;
        } else {
            gsrc = (const char*)(h_prev + (size_t)b0 * HSZ + (k4 - ISZ));
            srcStride = HSZ * 2;
        }
        const int dstOff = k4 * 2;                    // byte offset within LDS row
        #pragma unroll 4
        for (int r = 0; r < 32; ++r) {
            ushort4 v;
            if (isX) {
                float4 xv = *(const float4*)(gsrc + (size_t)r * srcStride);
                v.x = f2bf(xv.x); v.y = f2bf(xv.y); v.z = f2bf(xv.z); v.w = f2bf(xv.w);
            } else {
                v = *(const ushort4*)(gsrc + (size_t)r * srcStride);
            }
            *(ushort4*)(Alds + r * ROWB + dstOff) = v;
        }
    }
    __syncthreads();

    // ---- MFMA K-loop: gates tile [32 x 16] for gate w ----
    const int r0 = lane & 15;
    const int hi = lane >> 4;
    const int nw = w * HSZ + jb * 16 + r0;            // gate column index in [0,2048)
    const unsigned short* wp = Wcat + (size_t)nw * KSZ + hi * 8;
    const char* a0p = Alds + r0 * ROWB + hi * 16;
    const char* a1p = a0p + 16 * ROWB;
    f32x4 acc0 = {0.f, 0.f, 0.f, 0.f};
    f32x4 acc1 = {0.f, 0.f, 0.f, 0.f};
    #pragma unroll 8
    for (int it = 0; it < 32; ++it) {
        bf16x8 bf = *(const bf16x8*)(wp + it * 32);       // 16B global (L2-hot)
        bf16x8 a0 = *(const bf16x8*)(a0p + it * 64);      // ds_read_b128
        bf16x8 a1 = *(const bf16x8*)(a1p + it * 64);
        acc0 = __builtin_amdgcn_mfma_f32_16x16x32_bf16(a0, bf, acc0, 0, 0, 0);
        acc1 = __builtin_amdgcn_mfma_f32_16x16x32_bf16(a1, bf, acc1, 0, 0, 0);
    }

    // ---- exchange gates via LDS (add bias here) ----
    const float bv = bias[nw];
    #pragma unroll
    for (int j = 0; j < 4; ++j) {
        gbuf[w][hi * 4 + j][r0]      = acc0[j] + bv;   // D: row=(lane>>4)*4+j, col=lane&15
        gbuf[w][16 + hi * 4 + j][r0] = acc1[j] + bv;
    }
    __syncthreads();

    // ---- elementwise LSTM cell update + output projection partial ----
    const int r  = tid >> 3;          // 0..31
    const int jj = (tid & 7) * 2;     // 0..14
    const int jg = jb * 16 + jj;      // hidden index

    float i0 = sigf(gbuf[0][r][jj]);     float i1 = sigf(gbuf[0][r][jj + 1]);
    float f0 = sigf(gbuf[1][r][jj]);     float f1 = sigf(gbuf[1][r][jj + 1]);
    float g0 = tanh_f(gbuf[2][r][jj]);   float g1 = tanh_f(gbuf[2][r][jj + 1]);
    float o0 = sigf(gbuf[3][r][jj]);     float o1 = sigf(gbuf[3][r][jj + 1]);

    size_t cidx = (size_t)(b0 + r) * HSZ + jg;
    float2 cp = *(float2*)(c + cidx);
    float cn0 = f0 * cp.x + i0 * g0;
    float cn1 = f1 * cp.y + i1 * g1;
    *(float2*)(c + cidx) = make_float2(cn0, cn1);

    float hn0 = o0 * tanh_f(cn0);
    float hn1 = o1 * tanh_f(cn1);
    unsigned int hb = (unsigned int)f2bf(hn0) | ((unsigned int)f2bf(hn1) << 16);
    *(unsigned int*)(h_next + cidx) = hb;

    float partial = Wout[jg] * hn0 + Wout[jg + 1] * hn1;
    partial += __shfl_xor(partial, 1, 8);
    partial += __shfl_xor(partial, 2, 8);
    partial += __shfl_xor(partial, 4, 8);
    if ((tid & 7) == 0)
        atomicAdd(out + (size_t)t * BATCH + b0 + r, partial);
}

// ---------------- host launcher ----------------
extern "C" void kernel_launch(void* const* d_in, const int* in_sizes, int n_in,
                              void* d_out, int out_size, void* d_ws, size_t ws_size,
                              hipStream_t stream) {
    const float* x    = (const float*)d_in[0];
    const float* Wih  = (const float*)d_in[1];
    const float* Whh  = (const float*)d_in[2];
    const float* bih  = (const float*)d_in[3];
    const float* bhh  = (const float*)d_in[4];
    const float* Wout = (const float*)d_in[5];
    const float* bout = (const float*)d_in[6];
    // d_in[7] = future (0) — unused

    char* ws = (char*)d_ws;
    unsigned short* Wcat = (unsigned short*)(ws);
    float*          bias = (float*)(ws + 4194304);
    unsigned short* h0   = (unsigned short*)(ws + 4202496);
    unsigned short* h1   = (unsigned short*)(ws + 4464640);
    float*          c    = (float*)(ws + 4726784);
    float*          out  = (float*)d_out;

    pack_weights<<<2048, 256, 0, stream>>>(Wih, Whh, Wcat);
    init_state<<<2048, 256, 0, stream>>>(out, bout, c, h0, bias, bih, bhh);

    for (int t = 0; t < T_STEPS; ++t) {
        const unsigned short* hp = (t & 1) ? h1 : h0;
        unsigned short*       hn = (t & 1) ? h0 : h1;
        lstm_step<<<dim3(32, 8), 256, 0, stream>>>(x, Wcat, bias, Wout, hp, hn, c, out, t);
    }
}

// Round 3
// 17257.500 us; speedup vs baseline: 2.7402x; 2.7402x over previous
//
#include <hip/hip_runtime.h>

#define T_STEPS 2048
#define BATCH   256
#define ISZ     512
#define HSZ     512
#define GSZ     2048   // 4*H
#define KSZ     1024   // I + H
#define ROWB    2064   // LDS A row stride in bytes (1024 bf16 + 16B pad)

using bf16x8 = __attribute__((ext_vector_type(8))) __bf16;
using f32x4  = __attribute__((ext_vector_type(4))) float;

// ---------------- workspace layout (bytes) ----------------
// 0        : W_cat  bf16 [2048][1024]   (4 MB)
// 4194304  : bias   f32  [2048]         (8 KB)
// 4202496  : hbuf0  bf16 [256][512]     (256 KB)
// 4464640  : hbuf1  bf16 [256][512]     (256 KB)
// 4726784  : flags  u32  [16 groups][64 pad]  (4 KB)  flag[g][wgi] = steps done
// total 4730880 bytes

__device__ __forceinline__ unsigned short f2bf(float f) {
    unsigned int u = __float_as_uint(f);
    unsigned int r = (u + 0x7FFFu + ((u >> 16) & 1u)) >> 16;
    return (unsigned short)r;
}
__device__ __forceinline__ float sigf(float x)   { return 1.0f / (1.0f + __expf(-x)); }
__device__ __forceinline__ float tanh_f(float x) { return 2.0f / (1.0f + __expf(-2.0f * x)) - 1.0f; }

// ---------------- pack W_ih|W_hh -> bf16 W_cat ----------------
__global__ void pack_weights(const float* __restrict__ Wih,
                             const float* __restrict__ Whh,
                             unsigned short* __restrict__ Wcat) {
    int gid = blockIdx.x * blockDim.x + threadIdx.x;   // 0 .. 524287
    int n   = gid >> 8;
    int k4  = (gid & 255) * 4;
    const float* src = (k4 < ISZ) ? (Wih + (size_t)n * ISZ + k4)
                                  : (Whh + (size_t)n * HSZ + (k4 - ISZ));
    float4 v = *(const float4*)src;
    ushort4 o;
    o.x = f2bf(v.x); o.y = f2bf(v.y); o.z = f2bf(v.z); o.w = f2bf(v.w);
    *(ushort4*)(Wcat + (size_t)n * KSZ + k4) = o;
}

// ---------------- init: out=b_out, hbufs=0, flags=0, bias=b_ih+b_hh ----------------
__global__ void init_state(float* __restrict__ out, const float* __restrict__ b_out,
                           unsigned int* __restrict__ hbufs,   // both buffers, contiguous
                           unsigned int* __restrict__ flags,
                           float* __restrict__ bias,
                           const float* __restrict__ b_ih, const float* __restrict__ b_hh) {
    int gid = blockIdx.x * blockDim.x + threadIdx.x;
    float bo = b_out[0];
    if (gid < T_STEPS * BATCH) out[gid] = bo;
    if (gid < 131072) hbufs[gid] = 0u;      // 512 KB of h double-buffer
    if (gid < 1024)   flags[gid] = 0u;
    if (gid < GSZ)    bias[gid] = b_ih[gid] + b_hh[gid];
}

// ---------------- persistent LSTM kernel (plain launch, group-local sync) ----------------
// grid 256 WGs x 256 thr. group g = bid & 15 owns batch rows [g*16, g*16+16).
// WG wgi = bid >> 4 owns hidden cols [wgi*32, wgi*32+32); wave w = gate w.
// ~330 VGPR/wave -> 1 block/CU -> all 256 blocks resident at launch (no coop needed).
__global__ __launch_bounds__(256, 1) void lstm_persist(
    const float* __restrict__ x,
    const unsigned short* __restrict__ Wcat,
    const float* __restrict__ bias,
    const float* __restrict__ Wout,
    unsigned short* hbuf0,
    unsigned short* hbuf1,
    unsigned int* flags,
    float* __restrict__ out)
{
    __shared__ __align__(16) char Alds[16 * ROWB];   // 33 KB: A = [x_t | h] 16 rows
    __shared__ float gbuf[4][16][32];                // 8 KB gate exchange

    const int tid  = threadIdx.x;
    const int lane = tid & 63;
    const int w    = tid >> 6;           // wave index = gate (i,f,g,o)
    const int g    = blockIdx.x & 15;    // batch group
    const int wgi  = blockIdx.x >> 4;    // col-block 0..15
    const int r0   = lane & 15;
    const int hi   = lane >> 4;          // 0..3

    // ---- W fragments resident in registers: 2 col-frags x 32 k-iters x 16B ----
    const int n0 = w * HSZ + wgi * 32 + r0;   // gate column
    const int n1 = n0 + 16;
    bf16x8 wf0[32], wf1[32];
    #pragma unroll
    for (int it = 0; it < 32; ++it) {
        wf0[it] = *(const bf16x8*)(Wcat + (size_t)n0 * KSZ + it * 32 + hi * 8);
        wf1[it] = *(const bf16x8*)(Wcat + (size_t)n1 * KSZ + it * 32 + hi * 8);
    }
    const float bv0 = bias[n0];
    const float bv1 = bias[n1];

    // ---- pointwise mapping: thread -> (row pr, cols hcol, hcol+1) ----
    const int pr   = tid >> 4;           // 0..15
    const int cc   = (tid & 15) * 2;     // 0..30
    const int hcol = wgi * 32 + cc;
    const float wo0 = Wout[hcol], wo1 = Wout[hcol + 1];
    float c0 = 0.f, c1 = 0.f;            // cell state lives in registers all 2048 steps

    // ---- x prefetch registers (32 VGPR), preload t=0 ----
    float4 xr[8];
    {
        const float* xb = x + (size_t)(g * 16) * ISZ;
        #pragma unroll
        for (int i = 0; i < 8; ++i) {
            int u = tid + i * 256;
            xr[i] = *(const float4*)(xb + (u >> 7) * ISZ + (u & 127) * 4);
        }
    }

    unsigned int* flg = flags + g * 64;  // this group's 16 flag slots (own cacheline)

    #pragma unroll 1
    for (int t = 0; t < T_STEPS; ++t) {
        // -- 1. wave 0 waits until all 16 WGs of the group have published step t-1 --
        if (t > 0) {
            if (tid < 64) {
                const unsigned int* fp = flg + (tid & 15);
                const unsigned int tgt = (unsigned int)t;
                while (true) {
                    unsigned int v = __hip_atomic_load(fp, __ATOMIC_RELAXED,
                                                       __HIP_MEMORY_SCOPE_AGENT);
                    if (__all(v >= tgt)) break;
                    __builtin_amdgcn_s_sleep(2);
                }
                // acquire: orders + invalidates stale cache lines before h reads
                (void)__hip_atomic_load(fp, __ATOMIC_ACQUIRE, __HIP_MEMORY_SCOPE_AGENT);
            }
            __syncthreads();
        }

        // -- 2. stage h_{t-1} (coherent 8B loads) and x_t (from prefetch regs) into LDS --
        unsigned long long* hsrc = (unsigned long long*)((t & 1) ? hbuf0 : hbuf1);
        #pragma unroll
        for (int i = 0; i < 8; ++i) {
            int u = tid + i * 256;               // 0..2047 over 16 rows x 128 ulongs
            int row = u >> 7, c8 = u & 127;
            unsigned long long v = __hip_atomic_load(
                hsrc + (size_t)(g * 16 + row) * 128 + c8,
                __ATOMIC_RELAXED, __HIP_MEMORY_SCOPE_AGENT);
            *(unsigned long long*)(Alds + row * ROWB + 1024 + c8 * 8) = v;
        }
        #pragma unroll
        for (int i = 0; i < 8; ++i) {
            int u = tid + i * 256;               // 0..2047 over 16 rows x 128 float4
            int row = u >> 7, c4 = u & 127;
            float4 v = xr[i];
            ushort4 o;
            o.x = f2bf(v.x); o.y = f2bf(v.y); o.z = f2bf(v.z); o.w = f2bf(v.w);
            *(ushort4*)(Alds + row * ROWB + c4 * 8) = o;
        }
        __syncthreads();

        // -- 3. prefetch x_{t+1} into regs (hides HBM latency under MFMA) --
        {
            int tp = (t + 1 < T_STEPS) ? t + 1 : t;
            const float* xb = x + ((size_t)tp * BATCH + g * 16) * ISZ;
            #pragma unroll
            for (int i = 0; i < 8; ++i) {
                int u = tid + i * 256;
                xr[i] = *(const float4*)(xb + (u >> 7) * ISZ + (u & 127) * 4);
            }
        }

        // -- 4. MFMA: gates[16 rows x 32 cols] for gate w, K=1024, W from VGPRs --
        f32x4 acc0 = {0.f, 0.f, 0.f, 0.f};
        f32x4 acc1 = {0.f, 0.f, 0.f, 0.f};
        const char* ap = Alds + r0 * ROWB + hi * 16;
        #pragma unroll
        for (int it = 0; it < 32; ++it) {
            bf16x8 a = *(const bf16x8*)(ap + it * 64);   // one ds_read_b128, 2 MFMAs
            acc0 = __builtin_amdgcn_mfma_f32_16x16x32_bf16(a, wf0[it], acc0, 0, 0, 0);
            acc1 = __builtin_amdgcn_mfma_f32_16x16x32_bf16(a, wf1[it], acc1, 0, 0, 0);
        }

        // -- 5. exchange gates via LDS (D: row=(lane>>4)*4+j, col=lane&15) --
        #pragma unroll
        for (int j = 0; j < 4; ++j) {
            gbuf[w][hi * 4 + j][r0]      = acc0[j] + bv0;
            gbuf[w][hi * 4 + j][16 + r0] = acc1[j] + bv1;
        }
        __syncthreads();

        // -- 6. pointwise cell update (c in regs), h write (coherent), out partial --
        float iv0 = sigf(gbuf[0][pr][cc]),   iv1 = sigf(gbuf[0][pr][cc + 1]);
        float fv0 = sigf(gbuf[1][pr][cc]),   fv1 = sigf(gbuf[1][pr][cc + 1]);
        float gv0 = tanh_f(gbuf[2][pr][cc]), gv1 = tanh_f(gbuf[2][pr][cc + 1]);
        float ov0 = sigf(gbuf[3][pr][cc]),   ov1 = sigf(gbuf[3][pr][cc + 1]);
        c0 = fv0 * c0 + iv0 * gv0;
        c1 = fv1 * c1 + iv1 * gv1;
        float h0 = ov0 * tanh_f(c0);
        float h1 = ov1 * tanh_f(c1);

        unsigned int hb = (unsigned int)f2bf(h0) | ((unsigned int)f2bf(h1) << 16);
        unsigned int* hdst = (unsigned int*)((t & 1) ? hbuf1 : hbuf0);
        __hip_atomic_store(hdst + ((size_t)(g * 16 + pr) * HSZ + hcol) / 2, hb,
                           __ATOMIC_RELAXED, __HIP_MEMORY_SCOPE_AGENT);

        float pw = wo0 * h0 + wo1 * h1;
        pw += __shfl_xor(pw, 1, 16);
        pw += __shfl_xor(pw, 2, 16);
        pw += __shfl_xor(pw, 4, 16);
        pw += __shfl_xor(pw, 8, 16);
        if ((tid & 15) == 0)
            atomicAdd(out + (size_t)t * BATCH + g * 16 + pr, pw);

        // -- 7. barrier drains all waves' h stores, then release-publish step t --
        __syncthreads();
        if (tid == 0)
            __hip_atomic_store(flg + wgi, (unsigned int)(t + 1),
                               __ATOMIC_RELEASE, __HIP_MEMORY_SCOPE_AGENT);
    }
}

// ---------------- host launcher ----------------
extern "C" void kernel_launch(void* const* d_in, const int* in_sizes, int n_in,
                              void* d_out, int out_size, void* d_ws, size_t ws_size,
                              hipStream_t stream) {
    const float* x    = (const float*)d_in[0];
    const float* Wih  = (const float*)d_in[1];
    const float* Whh  = (const float*)d_in[2];
    const float* bih  = (const float*)d_in[3];
    const float* bhh  = (const float*)d_in[4];
    const float* Wout = (const float*)d_in[5];
    const float* bout = (const float*)d_in[6];

    char* ws = (char*)d_ws;
    unsigned short* Wcat  = (unsigned short*)(ws);
    float*          bias  = (float*)(ws + 4194304);
    unsigned short* h0    = (unsigned short*)(ws + 4202496);
    unsigned short* h1    = (unsigned short*)(ws + 4464640);
    unsigned int*   flags = (unsigned int*)(ws + 4726784);
    float*          out   = (float*)d_out;

    pack_weights<<<2048, 256, 0, stream>>>(Wih, Whh, Wcat);
    init_state<<<2048, 256, 0, stream>>>(out, bout, (unsigned int*)h0, flags, bias, bih, bhh);
    lstm_persist<<<256, 256, 0, stream>>>(x, Wcat, bias, Wout, h0, h1, flags, out);
}

// Round 6
// 9748.874 us; speedup vs baseline: 4.8507x; 1.7702x over previous
//
#include <hip/hip_runtime.h>

#define T_STEPS 2048
#define BATCH   256
#define ISZ     512
#define HSZ     512
#define GSZ     2048   // 4*H
#define KSZ     1024   // I + H
#define ROWB    2064   // LDS A row stride in bytes (1024 bf16 + 16B pad)

using bf16x8 = __attribute__((ext_vector_type(8))) __bf16;
using f32x4  = __attribute__((ext_vector_type(4))) float;
using i32x4  = __attribute__((ext_vector_type(4))) int;

// ---------------- workspace layout (bytes) ----------------
// 0        : W_cat  bf16 [2048][1024]        (4 MB)
// 4194304  : bias   f32  [2048]              (8 KB)
// 4202496  : thbuf0 u64  [256 rows][256]     (512 KB)  {2xbf16 h | u32 tag}
// 4726784  : thbuf1 u64  [256 rows][256]     (512 KB)
// total 5238784

__device__ __forceinline__ unsigned short f2bf(float f) {
    unsigned int u = __float_as_uint(f);
    unsigned int r = (u + 0x7FFFu + ((u >> 16) & 1u)) >> 16;
    return (unsigned short)r;
}
__device__ __forceinline__ float bf2f(unsigned int bits16) {
    return __uint_as_float(bits16 << 16);
}
__device__ __forceinline__ float sigf(float x)   { return 1.0f / (1.0f + __expf(-x)); }
__device__ __forceinline__ float tanh_f(float x) { return 2.0f / (1.0f + __expf(-2.0f * x)) - 1.0f; }

// ---------------- pack W_ih|W_hh -> bf16 W_cat ----------------
__global__ void pack_weights(const float* __restrict__ Wih,
                             const float* __restrict__ Whh,
                             unsigned short* __restrict__ Wcat) {
    int gid = blockIdx.x * blockDim.x + threadIdx.x;   // 0 .. 524287
    int n   = gid >> 8;
    int k4  = (gid & 255) * 4;
    const float* src = (k4 < ISZ) ? (Wih + (size_t)n * ISZ + k4)
                                  : (Whh + (size_t)n * HSZ + (k4 - ISZ));
    float4 v = *(const float4*)src;
    ushort4 o;
    o.x = f2bf(v.x); o.y = f2bf(v.y); o.z = f2bf(v.z); o.w = f2bf(v.w);
    *(ushort4*)(Wcat + (size_t)n * KSZ + k4) = o;
}

// ---------------- init: tagged h buffers = 0 (tag 0 < any target), bias ----------------
__global__ void init_state(unsigned int* __restrict__ thbufs,   // both buffers, 262144 u32
                           float* __restrict__ bias,
                           const float* __restrict__ b_ih, const float* __restrict__ b_hh) {
    int gid = blockIdx.x * blockDim.x + threadIdx.x;
    if (gid < 262144) thbufs[gid] = 0u;
    if (gid < GSZ)    bias[gid] = b_ih[gid] + b_hh[gid];
}

// ---------------- persistent LSTM kernel: tagged-word dataflow sync ----------------
// 256 WGs x 256 thr, 1 block/CU (full-register waves) -> all resident.
// group g = bid & 15 owns batch rows [g*16, g*16+16); WG wgi = bid>>4 owns
// hidden cols [wgi*32, wgi*32+32); wave w = gate w.
// Sync: h published as {2xbf16 | tag} 8B words via sc0 sc1 (MALL, placement-agnostic);
// consumers spin until their slice's tags reach t. Parity double-buffer gives the
// one-step slack that provably prevents overwrite-before-consume.
__global__ __launch_bounds__(256, 1) void lstm_persist(
    const float* __restrict__ x,
    const unsigned short* __restrict__ Wcat,
    const float* __restrict__ bias,
    const float* __restrict__ Wout,
    const float* __restrict__ bout,
    unsigned long long* thbuf0,
    unsigned long long* thbuf1,
    float* __restrict__ out)
{
    __shared__ __align__(16) char Alds[16 * ROWB];   // 33 KB: A = [x_t | h] 16 rows
    __shared__ float gbuf[4][16][32];                // 8 KB gate exchange
    __shared__ float obuf[4];                        // out-dot wave partials

    const int tid  = threadIdx.x;
    const int lane = tid & 63;
    const int w    = tid >> 6;           // wave index = gate (i,f,g,o)
    const int g    = blockIdx.x & 15;    // batch group
    const int wgi  = blockIdx.x >> 4;    // col-block 0..15
    const int r0   = lane & 15;
    const int hi   = lane >> 4;

    // ---- W fragments resident in registers (unified VGPR/AGPR file) ----
    const int n0 = w * HSZ + wgi * 32 + r0;
    const int n1 = n0 + 16;
    bf16x8 wf0[32], wf1[32];
    #pragma unroll
    for (int it = 0; it < 32; ++it) {
        wf0[it] = *(const bf16x8*)(Wcat + (size_t)n0 * KSZ + it * 32 + hi * 8);
        wf1[it] = *(const bf16x8*)(Wcat + (size_t)n1 * KSZ + it * 32 + hi * 8);
    }
    const float bv0 = bias[n0];
    const float bv1 = bias[n1];
    const float bo  = bout[0];

    // ---- pointwise mapping: thread -> (row pr, cols hcol, hcol+1) ----
    const int pr   = tid >> 4;           // 0..15
    const int cc   = (tid & 15) * 2;     // 0..30
    const int hcol = wgi * 32 + cc;
    float c0 = 0.f, c1 = 0.f;            // cell state in registers all 2048 steps

    // ---- out-dot mapping: thread -> cols (2*tid, 2*tid+1) of row wgi ----
    const float woA = Wout[tid * 2];
    const float woB = Wout[tid * 2 + 1];

    // ---- tagged-h addressing ----
    const unsigned long long tb0 = (unsigned long long)thbuf0;
    const unsigned long long tb1 = (unsigned long long)thbuf1;
    // probe: row (tid>>4), 16 consecutive u64 starting at word (tid&15)*16
    const unsigned long long poff =
        ((unsigned long long)(g * 16 + (tid >> 4)) * 256 + (tid & 15) * 16) * 8;
    // publish: row pr, word wgi*16 + (tid&15)
    const unsigned long long soff =
        ((unsigned long long)(g * 16 + pr) * 256 + wgi * 16 + (tid & 15)) * 8;

    // ---- x prefetch registers, preload t=0 ----
    float4 xr[8];
    {
        const float* xb = x + (size_t)(g * 16) * ISZ;
        #pragma unroll
        for (int i = 0; i < 8; ++i) {
            int u = tid + i * 256;
            xr[i] = *(const float4*)(xb + (u >> 7) * ISZ + (u & 127) * 4);
        }
    }

    #pragma unroll 1
    for (int t = 0; ; ++t) {
        // -- A: stage x_t (bf16) into LDS x-half from prefetch regs --
        if (t < T_STEPS) {
            #pragma unroll
            for (int i = 0; i < 8; ++i) {
                int u = tid + i * 256;
                int row = u >> 7, c4 = u & 127;
                float4 v = xr[i];
                ushort4 o;
                o.x = f2bf(v.x); o.y = f2bf(v.y); o.z = f2bf(v.z); o.w = f2bf(v.w);
                *(ushort4*)(Alds + row * ROWB + c4 * 8) = o;
            }
        }

        // -- B: acquire h_{t-1}: spin on tags, then stage to LDS h-half --
        char* hdst = Alds + (tid >> 4) * ROWB + 1024 + (tid & 15) * 64;
        if (t == 0) {
            i32x4 z = {0, 0, 0, 0};
            *(i32x4*)(hdst)      = z;
            *(i32x4*)(hdst + 16) = z;
            *(i32x4*)(hdst + 32) = z;
            *(i32x4*)(hdst + 48) = z;
        } else {
            const unsigned long long src = (((t - 1) & 1) ? tb1 : tb0) + poff;
            const int tgt = t;           // producer at t-1 stored tag t
            i32x4 q0, q1, q2, q3, q4, q5, q6, q7;
            // issue first probe, overlap flight with nothing-left-to-do VALU
            asm volatile(
                "global_load_dwordx4 %0, %8, off sc0 sc1\n\t"
                "global_load_dwordx4 %1, %8, off offset:16 sc0 sc1\n\t"
                "global_load_dwordx4 %2, %8, off offset:32 sc0 sc1\n\t"
                "global_load_dwordx4 %3, %8, off offset:48 sc0 sc1\n\t"
                "global_load_dwordx4 %4, %8, off offset:64 sc0 sc1\n\t"
                "global_load_dwordx4 %5, %8, off offset:80 sc0 sc1\n\t"
                "global_load_dwordx4 %6, %8, off offset:96 sc0 sc1\n\t"
                "global_load_dwordx4 %7, %8, off offset:112 sc0 sc1"
                : "=&v"(q0), "=&v"(q1), "=&v"(q2), "=&v"(q3),
                  "=&v"(q4), "=&v"(q5), "=&v"(q6), "=&v"(q7)
                : "v"(src) : "memory");
            while (true) {
                asm volatile("s_waitcnt vmcnt(0)" ::: "memory");
                __builtin_amdgcn_sched_barrier(0);
                bool ok = (q0[1] >= tgt) & (q0[3] >= tgt) & (q1[1] >= tgt) & (q1[3] >= tgt)
                        & (q2[1] >= tgt) & (q2[3] >= tgt) & (q3[1] >= tgt) & (q3[3] >= tgt)
                        & (q4[1] >= tgt) & (q4[3] >= tgt) & (q5[1] >= tgt) & (q5[3] >= tgt)
                        & (q6[1] >= tgt) & (q6[3] >= tgt) & (q7[1] >= tgt) & (q7[3] >= tgt);
                if (__all((int)ok)) break;
                asm volatile(
                    "global_load_dwordx4 %0, %8, off sc0 sc1\n\t"
                    "global_load_dwordx4 %1, %8, off offset:16 sc0 sc1\n\t"
                    "global_load_dwordx4 %2, %8, off offset:32 sc0 sc1\n\t"
                    "global_load_dwordx4 %3, %8, off offset:48 sc0 sc1\n\t"
                    "global_load_dwordx4 %4, %8, off offset:64 sc0 sc1\n\t"
                    "global_load_dwordx4 %5, %8, off offset:80 sc0 sc1\n\t"
                    "global_load_dwordx4 %6, %8, off offset:96 sc0 sc1\n\t"
                    "global_load_dwordx4 %7, %8, off offset:112 sc0 sc1"
                    : "=&v"(q0), "=&v"(q1), "=&v"(q2), "=&v"(q3),
                      "=&v"(q4), "=&v"(q5), "=&v"(q6), "=&v"(q7)
                    : "v"(src) : "memory");
            }
            // extract 16 h-pairs (x,z of each 16B) -> LDS h-half (64B/thread)
            i32x4 p0 = {q0[0], q0[2], q1[0], q1[2]};
            i32x4 p1 = {q2[0], q2[2], q3[0], q3[2]};
            i32x4 p2 = {q4[0], q4[2], q5[0], q5[2]};
            i32x4 p3 = {q6[0], q6[2], q7[0], q7[2]};
            *(i32x4*)(hdst)      = p0;
            *(i32x4*)(hdst + 16) = p1;
            *(i32x4*)(hdst + 32) = p2;
            *(i32x4*)(hdst + 48) = p3;
        }
        __syncthreads();   // C: A-tile (x_t | h_{t-1}) ready

        // -- D: out[t-1, g*16+wgi] = Wout . h_{t-1}[row wgi] + b_out --
        if (t > 0) {
            unsigned pairw = *(unsigned*)(Alds + wgi * ROWB + 1024 + tid * 4);
            float ph0 = bf2f(pairw & 0xffffu);
            float ph1 = bf2f(pairw >> 16);
            float ps = woA * ph0 + woB * ph1;
            ps += __shfl_xor(ps, 1);
            ps += __shfl_xor(ps, 2);
            ps += __shfl_xor(ps, 4);
            ps += __shfl_xor(ps, 8);
            ps += __shfl_xor(ps, 16);
            ps += __shfl_xor(ps, 32);
            if (lane == 0) obuf[w] = ps;
        }
        __syncthreads();   // D-bar: obuf complete (and Alds stable)
        if (t > 0 && tid == 0)
            out[(size_t)(t - 1) * BATCH + g * 16 + wgi] =
                obuf[0] + obuf[1] + obuf[2] + obuf[3] + bo;
        if (t == T_STEPS) break;

        // -- E: prefetch x_{t+1} into regs (lands under MFMA) --
        {
            int tp = (t + 1 < T_STEPS) ? t + 1 : T_STEPS - 1;
            const float* xb = x + ((size_t)tp * BATCH + g * 16) * ISZ;
            #pragma unroll
            for (int i = 0; i < 8; ++i) {
                int u = tid + i * 256;
                xr[i] = *(const float4*)(xb + (u >> 7) * ISZ + (u & 127) * 4);
            }
        }

        // -- F: MFMA, gates[16 x 32] for gate w, K=1024, 4 independent chains --
        f32x4 a0a = {0.f,0.f,0.f,0.f}, a0b = {0.f,0.f,0.f,0.f};
        f32x4 a1a = {0.f,0.f,0.f,0.f}, a1b = {0.f,0.f,0.f,0.f};
        const char* ap = Alds + r0 * ROWB + hi * 16;
        #pragma unroll
        for (int it = 0; it < 32; it += 2) {
            bf16x8 ae = *(const bf16x8*)(ap + it * 64);
            bf16x8 ao = *(const bf16x8*)(ap + it * 64 + 64);
            a0a = __builtin_amdgcn_mfma_f32_16x16x32_bf16(ae, wf0[it],     a0a, 0, 0, 0);
            a1a = __builtin_amdgcn_mfma_f32_16x16x32_bf16(ae, wf1[it],     a1a, 0, 0, 0);
            a0b = __builtin_amdgcn_mfma_f32_16x16x32_bf16(ao, wf0[it + 1], a0b, 0, 0, 0);
            a1b = __builtin_amdgcn_mfma_f32_16x16x32_bf16(ao, wf1[it + 1], a1b, 0, 0, 0);
        }

        // -- G: exchange gates via LDS (D-layout: row=(lane>>4)*4+j, col=lane&15) --
        #pragma unroll
        for (int j = 0; j < 4; ++j) {
            gbuf[w][hi * 4 + j][r0]      = a0a[j] + a0b[j] + bv0;
            gbuf[w][hi * 4 + j][16 + r0] = a1a[j] + a1b[j] + bv1;
        }
        __syncthreads();

        // -- H: pointwise cell update (c in regs), publish tagged h --
        float iv0 = sigf(gbuf[0][pr][cc]),   iv1 = sigf(gbuf[0][pr][cc + 1]);
        float fv0 = sigf(gbuf[1][pr][cc]),   fv1 = sigf(gbuf[1][pr][cc + 1]);
        float gv0 = tanh_f(gbuf[2][pr][cc]), gv1 = tanh_f(gbuf[2][pr][cc + 1]);
        float ov0 = sigf(gbuf[3][pr][cc]),   ov1 = sigf(gbuf[3][pr][cc + 1]);
        c0 = fv0 * c0 + iv0 * gv0;
        c1 = fv1 * c1 + iv1 * gv1;
        float h0f = ov0 * tanh_f(c0);
        float h1f = ov1 * tanh_f(c1);

        unsigned int hvb = (unsigned int)f2bf(h0f) | ((unsigned int)f2bf(h1f) << 16);
        unsigned long long hw = (unsigned long long)hvb
                              | ((unsigned long long)(unsigned)(t + 1) << 32);
        unsigned long long dst = ((t & 1) ? tb1 : tb0) + soff;
        asm volatile("global_store_dwordx2 %0, %1, off sc0 sc1"
                     :: "v"(dst), "v"(hw) : "memory");
        // fire-and-forget: next iteration's probe vmcnt(0) drains it.
    }
}

// ---------------- host launcher ----------------
extern "C" void kernel_launch(void* const* d_in, const int* in_sizes, int n_in,
                              void* d_out, int out_size, void* d_ws, size_t ws_size,
                              hipStream_t stream) {
    const float* x    = (const float*)d_in[0];
    const float* Wih  = (const float*)d_in[1];
    const float* Whh  = (const float*)d_in[2];
    const float* bih  = (const float*)d_in[3];
    const float* bhh  = (const float*)d_in[4];
    const float* Wout = (const float*)d_in[5];
    const float* bout = (const float*)d_in[6];

    char* ws = (char*)d_ws;
    unsigned short*     Wcat = (unsigned short*)(ws);
    float*              bias = (float*)(ws + 4194304);
    unsigned long long* th0  = (unsigned long long*)(ws + 4202496);
    unsigned long long* th1  = (unsigned long long*)(ws + 4726784);
    float*              out  = (float*)d_out;

    pack_weights<<<2048, 256, 0, stream>>>(Wih, Whh, Wcat);
    init_state<<<2048, 256, 0, stream>>>((unsigned int*)th0, bias, bih, bhh);
    lstm_persist<<<256, 256, 0, stream>>>(x, Wcat, bias, Wout, bout, th0, th1, out);
}

// Round 9
// 5479.963 us; speedup vs baseline: 8.6295x; 1.7790x over previous
//
#include <hip/hip_runtime.h>

#define T_STEPS 2048
#define BATCH   256
#define ISZ     512
#define HSZ     512
#define GSZ     2048   // 4*H
#define KSZ     1024   // I + H
#define XH      1040   // LDS row stride bytes (512 bf16 + 16B pad)

using bf16x8 = __attribute__((ext_vector_type(8))) __bf16;
using f32x4  = __attribute__((ext_vector_type(4))) float;
using i32x4  = __attribute__((ext_vector_type(4))) int;

// ---------------- workspace layout (bytes) ----------------
// 0        : W_cat  bf16 [2048][1024]        (4 MB)
// 4194304  : bias   f32  [2048]              (8 KB)
// 4202496  : thbuf0 u64  [256 rows][256]     (512 KB)  {2xbf16 h | u32 tag}
// 4726784  : thbuf1 u64  [256 rows][256]     (512 KB)

__device__ __forceinline__ unsigned short f2bf(float f) {
    unsigned int u = __float_as_uint(f);
    unsigned int r = (u + 0x7FFFu + ((u >> 16) & 1u)) >> 16;
    return (unsigned short)r;
}
__device__ __forceinline__ float bf2f(unsigned int bits16) {
    return __uint_as_float(bits16 << 16);
}
__device__ __forceinline__ float sigf(float x)   { return 1.0f / (1.0f + __expf(-x)); }
__device__ __forceinline__ float tanh_f(float x) { return 2.0f / (1.0f + __expf(-2.0f * x)) - 1.0f; }

// ---------------- pack W_ih|W_hh -> bf16 W_cat ----------------
__global__ void pack_weights(const float* __restrict__ Wih,
                             const float* __restrict__ Whh,
                             unsigned short* __restrict__ Wcat) {
    int gid = blockIdx.x * blockDim.x + threadIdx.x;   // 0 .. 524287
    int n   = gid >> 8;
    int k4  = (gid & 255) * 4;
    const float* src = (k4 < ISZ) ? (Wih + (size_t)n * ISZ + k4)
                                  : (Whh + (size_t)n * HSZ + (k4 - ISZ));
    float4 v = *(const float4*)src;
    ushort4 o;
    o.x = f2bf(v.x); o.y = f2bf(v.y); o.z = f2bf(v.z); o.w = f2bf(v.w);
    *(ushort4*)(Wcat + (size_t)n * KSZ + k4) = o;
}

// ---------------- init: tagged h buffers = 0, bias = b_ih + b_hh ----------------
__global__ void init_state(unsigned int* __restrict__ thbufs,   // both buffers, 262144 u32
                           float* __restrict__ bias,
                           const float* __restrict__ b_ih, const float* __restrict__ b_hh) {
    int gid = blockIdx.x * blockDim.x + threadIdx.x;
    if (gid < 262144) thbufs[gid] = 0u;
    if (gid < GSZ)    bias[gid] = b_ih[gid] + b_hh[gid];
}

// ---------------- persistent LSTM: wave-specialized split-K pipeline ----------------
// 256 WGs x 512 thr (8 waves, 2/SIMD). group g = bid&15 owns batch rows [g*16,+16);
// WG wgi = bid>>4 owns hidden cols [wgi*32,+32). Waves 0-3 (x-waves): gate w,
// K half [0,512) = x contribution. Waves 4-7 (h-waves): gate w-4, K half
// [512,1024) = h contribution, gated on the tagged probe.
//
// R9 invariant (fixes R7/R8 nondeterminism): NO inline-asm VMEM leaves in-flight
// register state across any compiler-visible statement boundary. Probe = ONE asm
// {8 loads + s_waitcnt vmcnt(0)} so outputs are genuinely defined at asm retire
// (the R7/R8 split form allowed regalloc to spill/reuse the destination regs
// before the loads landed -> timing-dependent garbage). Publish = ONE asm
// {store + s_waitcnt vmcnt(0)} so the data reg cannot be reused while the store
// is outstanding. Full __syncthreads() everywhere.
__global__ __launch_bounds__(512, 2) void lstm_persist(
    const float* __restrict__ x,
    const unsigned short* __restrict__ Wcat,
    const float* __restrict__ bias,
    const float* __restrict__ Wout,
    const float* __restrict__ bout,
    unsigned long long* thbuf0,
    unsigned long long* thbuf1,
    float* __restrict__ out)
{
    __shared__ __align__(16) char xlds0[16 * XH];   // x_t  bf16, double-buffered
    __shared__ __align__(16) char xlds1[16 * XH];
    __shared__ __align__(16) char hlds [16 * XH];   // h_{t-1} bf16
    __shared__ float gbuf[4][16][32];               // combined gates (x writes, h adds)
    __shared__ float obuf[4];                       // out-dot wave partials

    const int tid  = threadIdx.x;
    const int lane = tid & 63;
    const int w    = tid >> 6;           // 0..7
    const int gate = w & 3;
    const bool isx = (w < 4);
    const int g    = blockIdx.x & 15;
    const int wgi  = blockIdx.x >> 4;
    const int r0   = lane & 15;
    const int hi   = lane >> 4;          // 0..3

    // ---- W fragments: 16 k-iters x 2 col-frags = 128 VGPRs (resident) ----
    const int kb = isx ? 0 : 16;         // k-iter base (x half / h half)
    const int n0 = gate * HSZ + wgi * 32 + r0;
    const int n1 = n0 + 16;
    bf16x8 wf0[16], wf1[16];
    #pragma unroll
    for (int it = 0; it < 16; ++it) {
        wf0[it] = *(const bf16x8*)(Wcat + (size_t)n0 * KSZ + (kb + it) * 32 + hi * 8);
        wf1[it] = *(const bf16x8*)(Wcat + (size_t)n1 * KSZ + (kb + it) * 32 + hi * 8);
    }
    const float bv0 = bias[n0];
    const float bv1 = bias[n1];
    const float bo  = bout[0];

    // ---- pointwise mapping: thread -> (row tid>>5, col tid&31), 1 col each ----
    const int pr = tid >> 5;
    const int pc = tid & 31;
    float cst = 0.f;                     // cell state, 1 reg, all 2048 steps

    // ---- out-dot weights (x-wave threads 0..255: cols 2*tid, 2*tid+1) ----
    float woA = 0.f, woB = 0.f;
    if (isx) { woA = Wout[tid * 2]; woB = Wout[tid * 2 + 1]; }

    // ---- tagged-h addressing ----
    const int prow = (w - 4) * 4 + hi;   // h-waves: probed/staged row 0..15
    const unsigned long long tb0 = (unsigned long long)thbuf0;
    const unsigned long long tb1 = (unsigned long long)thbuf1;
    const unsigned long long poff =
        ((unsigned long long)(g * 16 + (isx ? 0 : prow)) * 256) * 8 + (unsigned)(r0 * 16);
    const unsigned long long soff =
        ((unsigned long long)(g * 16 + pr) * 256 + wgi * 16 + (pc >> 1)) * 8;

    // ---- x prefetch regs (x-waves): 8 float4 = this wave-row's full 2KB ----
    float4 xr[8];
    const int xrow = w * 4 + hi;         // x-waves: staged row 0..15

    // ---- prologue: stage x_0 into xlds0, prefetch x_1 ----
    if (isx) {
        const float* xb = x + ((size_t)(g * 16 + xrow)) * ISZ + r0 * 4;
        #pragma unroll
        for (int s = 0; s < 8; ++s) xr[s] = *(const float4*)(xb + s * 64);
        #pragma unroll
        for (int s = 0; s < 8; ++s) {
            float4 v = xr[s];
            ushort4 o;
            o.x = f2bf(v.x); o.y = f2bf(v.y); o.z = f2bf(v.z); o.w = f2bf(v.w);
            *(ushort4*)(xlds0 + xrow * XH + r0 * 8 + s * 128) = o;
        }
        const float* xb1 = x + ((size_t)BATCH + g * 16 + xrow) * ISZ + r0 * 4;
        #pragma unroll
        for (int s = 0; s < 8; ++s) xr[s] = *(const float4*)(xb1 + s * 64);
    }
    __syncthreads();

    #pragma unroll 1
    for (int t = 0; ; ++t) {
        if (isx) {
            if (t < T_STEPS) {
                // -- x-MFMA from xlds[t&1]: gates_x, K in [0,512) --
                f32x4 a0a = {0.f,0.f,0.f,0.f}, a0b = {0.f,0.f,0.f,0.f};
                f32x4 a1a = {0.f,0.f,0.f,0.f}, a1b = {0.f,0.f,0.f,0.f};
                const char* ap = ((t & 1) ? xlds1 : xlds0) + r0 * XH + hi * 16;
                #pragma unroll
                for (int it = 0; it < 16; it += 2) {
                    bf16x8 ae = *(const bf16x8*)(ap + it * 64);
                    bf16x8 ao = *(const bf16x8*)(ap + it * 64 + 64);
                    a0a = __builtin_amdgcn_mfma_f32_16x16x32_bf16(ae, wf0[it],   a0a, 0, 0, 0);
                    a1a = __builtin_amdgcn_mfma_f32_16x16x32_bf16(ae, wf1[it],   a1a, 0, 0, 0);
                    a0b = __builtin_amdgcn_mfma_f32_16x16x32_bf16(ao, wf0[it+1], a0b, 0, 0, 0);
                    a1b = __builtin_amdgcn_mfma_f32_16x16x32_bf16(ao, wf1[it+1], a1b, 0, 0, 0);
                }
                #pragma unroll
                for (int j = 0; j < 4; ++j) {
                    gbuf[gate][hi * 4 + j][r0]      = a0a[j] + a0b[j] + bv0;
                    gbuf[gate][hi * 4 + j][16 + r0] = a1a[j] + a1b[j] + bv1;
                }
                // -- stage x_{t+1}, prefetch x_{t+2} (plain C++ loads: compiler
                //    tracks their vmcnt correctly) --
                if (t + 1 < T_STEPS) {
                    char* xd = ((t + 1) & 1) ? xlds1 : xlds0;
                    #pragma unroll
                    for (int s = 0; s < 8; ++s) {
                        float4 v = xr[s];
                        ushort4 o;
                        o.x = f2bf(v.x); o.y = f2bf(v.y); o.z = f2bf(v.z); o.w = f2bf(v.w);
                        *(ushort4*)(xd + xrow * XH + r0 * 8 + s * 128) = o;
                    }
                    int tp = (t + 2 < T_STEPS) ? t + 2 : T_STEPS - 1;
                    const float* xb = x + ((size_t)tp * BATCH + g * 16 + xrow) * ISZ + r0 * 4;
                    #pragma unroll
                    for (int s = 0; s < 8; ++s) xr[s] = *(const float4*)(xb + s * 64);
                }
            }
        } else {
            char* hd = hlds + prow * XH + r0 * 8;
            if (t == 0) {
                #pragma unroll
                for (int s = 0; s < 8; ++s)
                    *(unsigned long long*)(hd + s * 128) = 0ull;
            } else {
                // -- probe h_{t-1}: SELF-CONTAINED asm {8 loads + vmcnt(0)} --
                // outputs are fully defined when the asm retires; retry loop
                // re-executes the whole block. No in-flight regs cross any
                // statement boundary.
                const unsigned long long psrc = (((t - 1) & 1) ? tb1 : tb0) + poff;
                const int tgt = t;
                i32x4 q0, q1, q2, q3, q4, q5, q6, q7;
                while (true) {
                    asm volatile(
                        "global_load_dwordx4 %0, %8, off sc0 sc1\n\t"
                        "global_load_dwordx4 %1, %8, off offset:256 sc0 sc1\n\t"
                        "global_load_dwordx4 %2, %8, off offset:512 sc0 sc1\n\t"
                        "global_load_dwordx4 %3, %8, off offset:768 sc0 sc1\n\t"
                        "global_load_dwordx4 %4, %8, off offset:1024 sc0 sc1\n\t"
                        "global_load_dwordx4 %5, %8, off offset:1280 sc0 sc1\n\t"
                        "global_load_dwordx4 %6, %8, off offset:1536 sc0 sc1\n\t"
                        "global_load_dwordx4 %7, %8, off offset:1792 sc0 sc1\n\t"
                        "s_waitcnt vmcnt(0)"
                        : "=&v"(q0), "=&v"(q1), "=&v"(q2), "=&v"(q3),
                          "=&v"(q4), "=&v"(q5), "=&v"(q6), "=&v"(q7)
                        : "v"(psrc) : "memory");
                    bool ok = (q0[1] >= tgt) & (q0[3] >= tgt) & (q1[1] >= tgt) & (q1[3] >= tgt)
                            & (q2[1] >= tgt) & (q2[3] >= tgt) & (q3[1] >= tgt) & (q3[3] >= tgt)
                            & (q4[1] >= tgt) & (q4[3] >= tgt) & (q5[1] >= tgt) & (q5[3] >= tgt)
                            & (q6[1] >= tgt) & (q6[3] >= tgt) & (q7[1] >= tgt) & (q7[3] >= tgt);
                    if (__all((int)ok)) {
                        // extract h pairs -> hlds (conflict-free b64 writes)
                        *(unsigned long long*)(hd +   0) = (unsigned long long)(unsigned)q0[0] | ((unsigned long long)(unsigned)q0[2] << 32);
                        *(unsigned long long*)(hd + 128) = (unsigned long long)(unsigned)q1[0] | ((unsigned long long)(unsigned)q1[2] << 32);
                        *(unsigned long long*)(hd + 256) = (unsigned long long)(unsigned)q2[0] | ((unsigned long long)(unsigned)q2[2] << 32);
                        *(unsigned long long*)(hd + 384) = (unsigned long long)(unsigned)q3[0] | ((unsigned long long)(unsigned)q3[2] << 32);
                        *(unsigned long long*)(hd + 512) = (unsigned long long)(unsigned)q4[0] | ((unsigned long long)(unsigned)q4[2] << 32);
                        *(unsigned long long*)(hd + 640) = (unsigned long long)(unsigned)q5[0] | ((unsigned long long)(unsigned)q5[2] << 32);
                        *(unsigned long long*)(hd + 768) = (unsigned long long)(unsigned)q6[0] | ((unsigned long long)(unsigned)q6[2] << 32);
                        *(unsigned long long*)(hd + 896) = (unsigned long long)(unsigned)q7[0] | ((unsigned long long)(unsigned)q7[2] << 32);
                        break;
                    }
                }
            }
        }
        __syncthreads();   // B2: hlds + gbuf(x half) ready

        if (isx) {
            if (t > 0) {
                // -- out[t-1] partials from hlds row wgi (shadow work) --
                unsigned pw2 = *(const unsigned*)(hlds + wgi * XH + tid * 4);
                float ps = woA * bf2f(pw2 & 0xffffu) + woB * bf2f(pw2 >> 16);
                ps += __shfl_xor(ps, 1);
                ps += __shfl_xor(ps, 2);
                ps += __shfl_xor(ps, 4);
                ps += __shfl_xor(ps, 8);
                ps += __shfl_xor(ps, 16);
                ps += __shfl_xor(ps, 32);
                if (lane == 0) obuf[w] = ps;
            }
        } else if (t < T_STEPS) {
            // -- h-MFMA from hlds: gates_h, K in [512,1024); RMW into gbuf --
            f32x4 a0a = {0.f,0.f,0.f,0.f}, a0b = {0.f,0.f,0.f,0.f};
            f32x4 a1a = {0.f,0.f,0.f,0.f}, a1b = {0.f,0.f,0.f,0.f};
            const char* ap = hlds + r0 * XH + hi * 16;
            #pragma unroll
            for (int it = 0; it < 16; it += 2) {
                bf16x8 ae = *(const bf16x8*)(ap + it * 64);
                bf16x8 ao = *(const bf16x8*)(ap + it * 64 + 64);
                a0a = __builtin_amdgcn_mfma_f32_16x16x32_bf16(ae, wf0[it],   a0a, 0, 0, 0);
                a1a = __builtin_amdgcn_mfma_f32_16x16x32_bf16(ae, wf1[it],   a1a, 0, 0, 0);
                a0b = __builtin_amdgcn_mfma_f32_16x16x32_bf16(ao, wf0[it+1], a0b, 0, 0, 0);
                a1b = __builtin_amdgcn_mfma_f32_16x16x32_bf16(ao, wf1[it+1], a1b, 0, 0, 0);
            }
            #pragma unroll
            for (int j = 0; j < 4; ++j) {
                gbuf[gate][hi * 4 + j][r0]      += a0a[j] + a0b[j];
                gbuf[gate][hi * 4 + j][16 + r0] += a1a[j] + a1b[j];
            }
        }
        __syncthreads();   // B3: gbuf complete, obuf ready

        if (t > 0 && tid == 0)
            out[(size_t)(t - 1) * BATCH + g * 16 + wgi] =
                obuf[0] + obuf[1] + obuf[2] + obuf[3] + bo;
        if (t == T_STEPS) break;

        // -- pointwise: 1 (row,col) per thread; c in reg; publish tagged h --
        {
            float iv = sigf(gbuf[0][pr][pc]);
            float fv = sigf(gbuf[1][pr][pc]);
            float gv = tanh_f(gbuf[2][pr][pc]);
            float ov = sigf(gbuf[3][pr][pc]);
            cst = fv * cst + iv * gv;
            float hval = ov * tanh_f(cst);
            unsigned hb16 = (unsigned)f2bf(hval);
            unsigned partner = __shfl_xor(hb16, 1);
            if (!(tid & 1)) {
                unsigned hv2 = hb16 | (partner << 16);
                unsigned long long word = (unsigned long long)hv2
                                        | ((unsigned long long)(unsigned)(t + 1) << 32);
                unsigned long long dst = ((t & 1) ? tb1 : tb0) + soff;
                // SELF-CONTAINED publish: store + drain in one asm so the data
                // register cannot be reused while the store is outstanding.
                // (No extra cost: B1's __syncthreads drains vmcnt anyway.)
                asm volatile("global_store_dwordx2 %0, %1, off sc0 sc1\n\t"
                             "s_waitcnt vmcnt(0)"
                             :: "v"(dst), "v"(word) : "memory");
            }
        }
        __syncthreads();   // B1: step boundary
    }
}

// ---------------- host launcher ----------------
extern "C" void kernel_launch(void* const* d_in, const int* in_sizes, int n_in,
                              void* d_out, int out_size, void* d_ws, size_t ws_size,
                              hipStream_t stream) {
    const float* x    = (const float*)d_in[0];
    const float* Wih  = (const float*)d_in[1];
    const float* Whh  = (const float*)d_in[2];
    const float* bih  = (const float*)d_in[3];
    const float* bhh  = (const float*)d_in[4];
    const float* Wout = (const float*)d_in[5];
    const float* bout = (const float*)d_in[6];

    char* ws = (char*)d_ws;
    unsigned short*     Wcat = (unsigned short*)(ws);
    float*              bias = (float*)(ws + 4194304);
    unsigned long long* th0  = (unsigned long long*)(ws + 4202496);
    unsigned long long* th1  = (unsigned long long*)(ws + 4726784);
    float*              out  = (float*)d_out;

    pack_weights<<<2048, 256, 0, stream>>>(Wih, Whh, Wcat);
    init_state<<<2048, 256, 0, stream>>>((unsigned int*)th0, bias, bih, bhh);
    lstm_persist<<<256, 512, 0, stream>>>(x, Wcat, bias, Wout, bout, th0, th1, out);
}

// Round 10
// 5163.666 us; speedup vs baseline: 9.1580x; 1.0613x over previous
//
#include <hip/hip_runtime.h>

#define T_STEPS 2048
#define BATCH   256
#define ISZ     512
#define HSZ     512
#define GSZ     2048   // 4*H
#define KSZ     1024   // I + H
#define XH      1024   // LDS row stride bytes (512 bf16, swizzled, no pad)

// T2 XOR swizzle: spreads the 16B column slots of 8 consecutive rows across
// 8 distinct bank groups (G4). Bits 4-6 of the byte col XOR row&7.
#define SWZ(row, col) ((col) ^ (((row) & 7) << 4))

using bf16x8 = __attribute__((ext_vector_type(8))) __bf16;
using f32x4  = __attribute__((ext_vector_type(4))) float;
using i32x4  = __attribute__((ext_vector_type(4))) int;

// ---------------- workspace layout (bytes) ----------------
// 0        : W_cat  bf16 [2048][1024]        (4 MB)
// 4194304  : bias   f32  [2048]              (8 KB)
// 4202496  : thbuf0 u64  [256 rows][256]     (512 KB)  {2xbf16 h | u32 tag}
// 4726784  : thbuf1 u64  [256 rows][256]     (512 KB)

__device__ __forceinline__ unsigned short f2bf(float f) {
    unsigned int u = __float_as_uint(f);
    unsigned int r = (u + 0x7FFFu + ((u >> 16) & 1u)) >> 16;
    return (unsigned short)r;
}
__device__ __forceinline__ float bf2f(unsigned int bits16) {
    return __uint_as_float(bits16 << 16);
}
__device__ __forceinline__ float sigf(float x)   { return 1.0f / (1.0f + __expf(-x)); }
__device__ __forceinline__ float tanh_f(float x) { return 2.0f / (1.0f + __expf(-2.0f * x)) - 1.0f; }

// ---------------- pack W_ih|W_hh -> bf16 W_cat ----------------
__global__ void pack_weights(const float* __restrict__ Wih,
                             const float* __restrict__ Whh,
                             unsigned short* __restrict__ Wcat) {
    int gid = blockIdx.x * blockDim.x + threadIdx.x;   // 0 .. 524287
    int n   = gid >> 8;
    int k4  = (gid & 255) * 4;
    const float* src = (k4 < ISZ) ? (Wih + (size_t)n * ISZ + k4)
                                  : (Whh + (size_t)n * HSZ + (k4 - ISZ));
    float4 v = *(const float4*)src;
    ushort4 o;
    o.x = f2bf(v.x); o.y = f2bf(v.y); o.z = f2bf(v.z); o.w = f2bf(v.w);
    *(ushort4*)(Wcat + (size_t)n * KSZ + k4) = o;
}

// ---------------- init: tagged h buffers = 0, bias = b_ih + b_hh ----------------
__global__ void init_state(unsigned int* __restrict__ thbufs,   // both buffers, 262144 u32
                           float* __restrict__ bias,
                           const float* __restrict__ b_ih, const float* __restrict__ b_hh) {
    int gid = blockIdx.x * blockDim.x + threadIdx.x;
    if (gid < 262144) thbufs[gid] = 0u;
    if (gid < GSZ)    bias[gid] = b_ih[gid] + b_hh[gid];
}

// ---------------- persistent LSTM: wave-specialized split-K pipeline ----------------
// 256 WGs x 512 thr (8 waves, 2/SIMD). group g = bid&15 owns batch rows [g*16,+16);
// WG wgi = bid>>4 owns hidden cols [wgi*32,+32). Waves 0-3 (x-waves): gate w,
// K half [0,512) = x contribution. Waves 4-7 (h-waves): gate w-4, K half
// [512,1024) = h contribution, gated on the tagged probe.
//
// R9 invariant (kept): NO inline-asm VMEM leaves in-flight register state across
// any compiler-visible statement boundary (probe = one asm {loads+vmcnt(0)};
// publish = one asm {store+vmcnt(0)}). Full __syncthreads() everywhere.
//
// R10 changes: (1) weight fragments PINNED in registers via opaque asm touch —
// R9's VGPR=120 proved the compiler rematerialized the W loads per step,
// streaming 256KB/WG/step from L2 (~24 TB/s, ~70% of L2 ceiling = the
// bottleneck). (2) XOR-swizzled LDS (XH=1024, col^=(row&7)<<4) kills the 8-way
// bank conflicts on ds_read_b128 frag reads (3.7e8 conflict counter).
// (3) gbuf rows padded 32->35 floats (write conflicts 4-way -> <=2-way).
__global__ __launch_bounds__(512, 2) void lstm_persist(
    const float* __restrict__ x,
    const unsigned short* __restrict__ Wcat,
    const float* __restrict__ bias,
    const float* __restrict__ Wout,
    const float* __restrict__ bout,
    unsigned long long* thbuf0,
    unsigned long long* thbuf1,
    float* __restrict__ out)
{
    __shared__ __align__(16) char xlds0[16 * XH];   // x_t  bf16, double-buffered
    __shared__ __align__(16) char xlds1[16 * XH];
    __shared__ __align__(16) char hlds [16 * XH];   // h_{t-1} bf16
    __shared__ float gbuf[4][16][35];               // combined gates (padded rows)
    __shared__ float obuf[4];                       // out-dot wave partials

    const int tid  = threadIdx.x;
    const int lane = tid & 63;
    const int w    = tid >> 6;           // 0..7
    const int gate = w & 3;
    const bool isx = (w < 4);
    const int g    = blockIdx.x & 15;
    const int wgi  = blockIdx.x >> 4;
    const int r0   = lane & 15;
    const int hi   = lane >> 4;          // 0..3

    // ---- W fragments: 16 k-iters x 2 col-frags = 128 VGPRs, PINNED resident ----
    const int kb = isx ? 0 : 16;         // k-iter base (x half / h half)
    const int n0 = gate * HSZ + wgi * 32 + r0;
    const int n1 = n0 + 16;
    bf16x8 wf0[16], wf1[16];
    #pragma unroll
    for (int it = 0; it < 16; ++it) {
        wf0[it] = *(const bf16x8*)(Wcat + (size_t)n0 * KSZ + (kb + it) * 32 + hi * 8);
        wf1[it] = *(const bf16x8*)(Wcat + (size_t)n1 * KSZ + (kb + it) * 32 + hi * 8);
    }
    // Opaque touch: values become asm-defined -> compiler cannot rematerialize
    // the loads inside the loop; they must stay register-resident.
    #pragma unroll
    for (int it = 0; it < 16; ++it) {
        asm volatile("" : "+v"(wf0[it]));
        asm volatile("" : "+v"(wf1[it]));
    }
    const float bv0 = bias[n0];
    const float bv1 = bias[n1];
    const float bo  = bout[0];

    // ---- pointwise mapping: thread -> (row tid>>5, col tid&31), 1 col each ----
    const int pr = tid >> 5;
    const int pc = tid & 31;
    float cst = 0.f;                     // cell state, 1 reg, all 2048 steps

    // ---- out-dot weights (x-wave threads 0..255: cols 2*tid, 2*tid+1) ----
    float woA = 0.f, woB = 0.f;
    if (isx) { woA = Wout[tid * 2]; woB = Wout[tid * 2 + 1]; }

    // ---- tagged-h addressing ----
    const int prow = (w - 4) * 4 + hi;   // h-waves: probed/staged row 0..15
    const unsigned long long tb0 = (unsigned long long)thbuf0;
    const unsigned long long tb1 = (unsigned long long)thbuf1;
    const unsigned long long poff =
        ((unsigned long long)(g * 16 + (isx ? 0 : prow)) * 256) * 8 + (unsigned)(r0 * 16);
    const unsigned long long soff =
        ((unsigned long long)(g * 16 + pr) * 256 + wgi * 16 + (pc >> 1)) * 8;

    // ---- swizzle constants ----
    const int xorv = (r0 & 7) << 4;      // frag-read XOR (row = r0)

    // ---- x prefetch regs (x-waves): 8 float4 = this wave-row's full 2KB ----
    float4 xr[8];
    const int xrow = w * 4 + hi;         // x-waves: staged row 0..15
    const int xwoff = SWZ(xrow, r0 * 8); // staged-write base col (s*128 adds above bit6)

    // ---- prologue: stage x_0 into xlds0, prefetch x_1 ----
    if (isx) {
        const float* xb = x + ((size_t)(g * 16 + xrow)) * ISZ + r0 * 4;
        #pragma unroll
        for (int s = 0; s < 8; ++s) xr[s] = *(const float4*)(xb + s * 64);
        #pragma unroll
        for (int s = 0; s < 8; ++s) {
            float4 v = xr[s];
            ushort4 o;
            o.x = f2bf(v.x); o.y = f2bf(v.y); o.z = f2bf(v.z); o.w = f2bf(v.w);
            *(ushort4*)(xlds0 + xrow * XH + xwoff + s * 128) = o;
        }
        const float* xb1 = x + ((size_t)BATCH + g * 16 + xrow) * ISZ + r0 * 4;
        #pragma unroll
        for (int s = 0; s < 8; ++s) xr[s] = *(const float4*)(xb1 + s * 64);
    }
    __syncthreads();

    #pragma unroll 1
    for (int t = 0; ; ++t) {
        if (isx) {
            if (t < T_STEPS) {
                // -- x-MFMA from xlds[t&1]: gates_x, K in [0,512) --
                f32x4 a0a = {0.f,0.f,0.f,0.f}, a0b = {0.f,0.f,0.f,0.f};
                f32x4 a1a = {0.f,0.f,0.f,0.f}, a1b = {0.f,0.f,0.f,0.f};
                const char* xsrc = ((t & 1) ? xlds1 : xlds0) + r0 * XH;
                #pragma unroll
                for (int it = 0; it < 16; it += 2) {
                    bf16x8 ae = *(const bf16x8*)(xsrc + ((hi * 16 + it * 64) ^ xorv));
                    bf16x8 ao = *(const bf16x8*)(xsrc + ((hi * 16 + (it + 1) * 64) ^ xorv));
                    a0a = __builtin_amdgcn_mfma_f32_16x16x32_bf16(ae, wf0[it],   a0a, 0, 0, 0);
                    a1a = __builtin_amdgcn_mfma_f32_16x16x32_bf16(ae, wf1[it],   a1a, 0, 0, 0);
                    a0b = __builtin_amdgcn_mfma_f32_16x16x32_bf16(ao, wf0[it+1], a0b, 0, 0, 0);
                    a1b = __builtin_amdgcn_mfma_f32_16x16x32_bf16(ao, wf1[it+1], a1b, 0, 0, 0);
                }
                #pragma unroll
                for (int j = 0; j < 4; ++j) {
                    gbuf[gate][hi * 4 + j][r0]      = a0a[j] + a0b[j] + bv0;
                    gbuf[gate][hi * 4 + j][16 + r0] = a1a[j] + a1b[j] + bv1;
                }
                // -- stage x_{t+1}, prefetch x_{t+2} --
                if (t + 1 < T_STEPS) {
                    char* xd = (((t + 1) & 1) ? xlds1 : xlds0) + xrow * XH + xwoff;
                    #pragma unroll
                    for (int s = 0; s < 8; ++s) {
                        float4 v = xr[s];
                        ushort4 o;
                        o.x = f2bf(v.x); o.y = f2bf(v.y); o.z = f2bf(v.z); o.w = f2bf(v.w);
                        *(ushort4*)(xd + s * 128) = o;
                    }
                    int tp = (t + 2 < T_STEPS) ? t + 2 : T_STEPS - 1;
                    const float* xb = x + ((size_t)tp * BATCH + g * 16 + xrow) * ISZ + r0 * 4;
                    #pragma unroll
                    for (int s = 0; s < 8; ++s) xr[s] = *(const float4*)(xb + s * 64);
                }
            }
        } else {
            char* hd = hlds + prow * XH + (SWZ(prow, r0 * 8));  // + s*128 stays above bit 6
            if (t == 0) {
                #pragma unroll
                for (int s = 0; s < 8; ++s)
                    *(unsigned long long*)(hd + s * 128) = 0ull;
            } else {
                // -- probe h_{t-1}: SELF-CONTAINED asm {8 loads + vmcnt(0)} --
                const unsigned long long psrc = (((t - 1) & 1) ? tb1 : tb0) + poff;
                const int tgt = t;
                i32x4 q0, q1, q2, q3, q4, q5, q6, q7;
                while (true) {
                    asm volatile(
                        "global_load_dwordx4 %0, %8, off sc0 sc1\n\t"
                        "global_load_dwordx4 %1, %8, off offset:256 sc0 sc1\n\t"
                        "global_load_dwordx4 %2, %8, off offset:512 sc0 sc1\n\t"
                        "global_load_dwordx4 %3, %8, off offset:768 sc0 sc1\n\t"
                        "global_load_dwordx4 %4, %8, off offset:1024 sc0 sc1\n\t"
                        "global_load_dwordx4 %5, %8, off offset:1280 sc0 sc1\n\t"
                        "global_load_dwordx4 %6, %8, off offset:1536 sc0 sc1\n\t"
                        "global_load_dwordx4 %7, %8, off offset:1792 sc0 sc1\n\t"
                        "s_waitcnt vmcnt(0)"
                        : "=&v"(q0), "=&v"(q1), "=&v"(q2), "=&v"(q3),
                          "=&v"(q4), "=&v"(q5), "=&v"(q6), "=&v"(q7)
                        : "v"(psrc) : "memory");
                    bool ok = (q0[1] >= tgt) & (q0[3] >= tgt) & (q1[1] >= tgt) & (q1[3] >= tgt)
                            & (q2[1] >= tgt) & (q2[3] >= tgt) & (q3[1] >= tgt) & (q3[3] >= tgt)
                            & (q4[1] >= tgt) & (q4[3] >= tgt) & (q5[1] >= tgt) & (q5[3] >= tgt)
                            & (q6[1] >= tgt) & (q6[3] >= tgt) & (q7[1] >= tgt) & (q7[3] >= tgt);
                    if (__all((int)ok)) {
                        // extract h pairs -> hlds (swizzled b64 writes)
                        *(unsigned long long*)(hd +   0) = (unsigned long long)(unsigned)q0[0] | ((unsigned long long)(unsigned)q0[2] << 32);
                        *(unsigned long long*)(hd + 128) = (unsigned long long)(unsigned)q1[0] | ((unsigned long long)(unsigned)q1[2] << 32);
                        *(unsigned long long*)(hd + 256) = (unsigned long long)(unsigned)q2[0] | ((unsigned long long)(unsigned)q2[2] << 32);
                        *(unsigned long long*)(hd + 384) = (unsigned long long)(unsigned)q3[0] | ((unsigned long long)(unsigned)q3[2] << 32);
                        *(unsigned long long*)(hd + 512) = (unsigned long long)(unsigned)q4[0] | ((unsigned long long)(unsigned)q4[2] << 32);
                        *(unsigned long long*)(hd + 640) = (unsigned long long)(unsigned)q5[0] | ((unsigned long long)(unsigned)q5[2] << 32);
                        *(unsigned long long*)(hd + 768) = (unsigned long long)(unsigned)q6[0] | ((unsigned long long)(unsigned)q6[2] << 32);
                        *(unsigned long long*)(hd + 896) = (unsigned long long)(unsigned)q7[0] | ((unsigned long long)(unsigned)q7[2] << 32);
                        break;
                    }
                }
            }
        }
        __syncthreads();   // B2: hlds + gbuf(x half) ready

        if (isx) {
            if (t > 0) {
                // -- out[t-1] partials from hlds row wgi (shadow work) --
                unsigned pw2 = *(const unsigned*)(hlds + wgi * XH + (SWZ(wgi, tid * 4)));
                float ps = woA * bf2f(pw2 & 0xffffu) + woB * bf2f(pw2 >> 16);
                ps += __shfl_xor(ps, 1);
                ps += __shfl_xor(ps, 2);
                ps += __shfl_xor(ps, 4);
                ps += __shfl_xor(ps, 8);
                ps += __shfl_xor(ps, 16);
                ps += __shfl_xor(ps, 32);
                if (lane == 0) obuf[w] = ps;
            }
        } else if (t < T_STEPS) {
            // -- h-MFMA from hlds: gates_h, K in [512,1024); RMW into gbuf --
            f32x4 a0a = {0.f,0.f,0.f,0.f}, a0b = {0.f,0.f,0.f,0.f};
            f32x4 a1a = {0.f,0.f,0.f,0.f}, a1b = {0.f,0.f,0.f,0.f};
            const char* hsrc = hlds + r0 * XH;
            #pragma unroll
            for (int it = 0; it < 16; it += 2) {
                bf16x8 ae = *(const bf16x8*)(hsrc + ((hi * 16 + it * 64) ^ xorv));
                bf16x8 ao = *(const bf16x8*)(hsrc + ((hi * 16 + (it + 1) * 64) ^ xorv));
                a0a = __builtin_amdgcn_mfma_f32_16x16x32_bf16(ae, wf0[it],   a0a, 0, 0, 0);
                a1a = __builtin_amdgcn_mfma_f32_16x16x32_bf16(ae, wf1[it],   a1a, 0, 0, 0);
                a0b = __builtin_amdgcn_mfma_f32_16x16x32_bf16(ao, wf0[it+1], a0b, 0, 0, 0);
                a1b = __builtin_amdgcn_mfma_f32_16x16x32_bf16(ao, wf1[it+1], a1b, 0, 0, 0);
            }
            #pragma unroll
            for (int j = 0; j < 4; ++j) {
                gbuf[gate][hi * 4 + j][r0]      += a0a[j] + a0b[j];
                gbuf[gate][hi * 4 + j][16 + r0] += a1a[j] + a1b[j];
            }
        }
        __syncthreads();   // B3: gbuf complete, obuf ready

        if (t > 0 && tid == 0)
            out[(size_t)(t - 1) * BATCH + g * 16 + wgi] =
                obuf[0] + obuf[1] + obuf[2] + obuf[3] + bo;
        if (t == T_STEPS) break;

        // -- pointwise: 1 (row,col) per thread; c in reg; publish tagged h --
        {
            float iv = sigf(gbuf[0][pr][pc]);
            float fv = sigf(gbuf[1][pr][pc]);
            float gv = tanh_f(gbuf[2][pr][pc]);
            float ov = sigf(gbuf[3][pr][pc]);
            cst = fv * cst + iv * gv;
            float hval = ov * tanh_f(cst);
            unsigned hb16 = (unsigned)f2bf(hval);
            unsigned partner = __shfl_xor(hb16, 1);
            if (!(tid & 1)) {
                unsigned hv2 = hb16 | (partner << 16);
                unsigned long long word = (unsigned long long)hv2
                                        | ((unsigned long long)(unsigned)(t + 1) << 32);
                unsigned long long dst = ((t & 1) ? tb1 : tb0) + soff;
                // SELF-CONTAINED publish: store + drain in one asm.
                asm volatile("global_store_dwordx2 %0, %1, off sc0 sc1\n\t"
                             "s_waitcnt vmcnt(0)"
                             :: "v"(dst), "v"(word) : "memory");
            }
        }
        __syncthreads();   // B1: step boundary
    }
}

// ---------------- host launcher ----------------
extern "C" void kernel_launch(void* const* d_in, const int* in_sizes, int n_in,
                              void* d_out, int out_size, void* d_ws, size_t ws_size,
                              hipStream_t stream) {
    const float* x    = (const float*)d_in[0];
    const float* Wih  = (const float*)d_in[1];
    const float* Whh  = (const float*)d_in[2];
    const float* bih  = (const float*)d_in[3];
    const float* bhh  = (const float*)d_in[4];
    const float* Wout = (const float*)d_in[5];
    const float* bout = (const float*)d_in[6];

    char* ws = (char*)d_ws;
    unsigned short*     Wcat = (unsigned short*)(ws);
    float*              bias = (float*)(ws + 4194304);
    unsigned long long* th0  = (unsigned long long*)(ws + 4202496);
    unsigned long long* th1  = (unsigned long long*)(ws + 4726784);
    float*              out  = (float*)d_out;

    pack_weights<<<2048, 256, 0, stream>>>(Wih, Whh, Wcat);
    init_state<<<2048, 256, 0, stream>>>((unsigned int*)th0, bias, bih, bhh);
    lstm_persist<<<256, 512, 0, stream>>>(x, Wcat, bias, Wout, bout, th0, th1, out);
}